// Round 1
// baseline (456.975 us; speedup 1.0000x reference)
//
#include <hip/hip_runtime.h>
#include <cstdint>

#define EPS 1e-5f

// ---- workspace layout (bytes) ----
#define A1_OFF   0ull                 // 8192*196 u16  (a1 bitmasks, 16 ch)
#define A2_OFF   3211264ull           // 8192*25  u32  (a2 bitmasks, 32 ch)
#define W2M_OFF  4030464ull           // 32*25 u32
#define W3M_OFF  4033664ull           // 64*25 u32
#define FW1M_OFF 4040064ull           // 128 u64
#define FW2M_OFF 4041088ull           // 128*2 u64
#define FW3M_OFF 4043136ull           // 10*2 u64
#define T1_OFF   4043296ull           // 16 f32
#define T2_OFF   4043360ull           // 32 f32
#define T3_OFF   4043488ull           // 64 f32
#define TC1_OFF  4043744ull           // 128 f32
#define TC2_OFF  4044256ull           // 128 f32

// ---------------------------------------------------------------------------
// Setup: pack binarized weights into bitmasks, fold bn+bias into thresholds.
// sign test used everywhere: value > thr  <=>  bn(value+bias) > 0  (g > 0)
// ---------------------------------------------------------------------------
__global__ void setup_kernel(
    const float* __restrict__ w2, const float* __restrict__ w3,
    const float* __restrict__ fw1, const float* __restrict__ fw2,
    const float* __restrict__ fw3,
    const float* __restrict__ b1, const float* __restrict__ g1,
    const float* __restrict__ be1, const float* __restrict__ m1,
    const float* __restrict__ v1,
    const float* __restrict__ b2, const float* __restrict__ g2,
    const float* __restrict__ be2, const float* __restrict__ m2,
    const float* __restrict__ v2,
    const float* __restrict__ b3, const float* __restrict__ g3,
    const float* __restrict__ be3, const float* __restrict__ m3,
    const float* __restrict__ v3,
    const float* __restrict__ fb1, const float* __restrict__ cm1,
    const float* __restrict__ fb2, const float* __restrict__ cm2,
    unsigned int* __restrict__ w2m, unsigned int* __restrict__ w3m,
    unsigned long long* __restrict__ fw1m, unsigned long long* __restrict__ fw2m,
    unsigned long long* __restrict__ fw3m,
    float* __restrict__ t1, float* __restrict__ t2, float* __restrict__ t3,
    float* __restrict__ tc1, float* __restrict__ tc2)
{
    int tid = threadIdx.x;
    if (tid < 16) t1[tid] = m1[tid] - be1[tid]*sqrtf(v1[tid]+EPS)/g1[tid] - b1[tid];
    if (tid < 32) t2[tid] = m2[tid] - be2[tid]*sqrtf(v2[tid]+EPS)/g2[tid] - b2[tid];
    if (tid < 64) t3[tid] = m3[tid] - be3[tid]*sqrtf(v3[tid]+EPS)/g3[tid] - b3[tid];
    if (tid < 128) { tc1[tid] = cm1[tid] - fb1[tid]; tc2[tid] = cm2[tid] - fb2[tid]; }

    for (int t = tid; t < 32*25; t += 256) {        // w2: (32,16,5,5)
        int oc = t / 25, pos = t % 25;
        unsigned int mk = 0;
        for (int ic = 0; ic < 16; ++ic)
            if (w2[(oc*16 + ic)*25 + pos] > 0.0f) mk |= 1u << ic;
        w2m[t] = mk;
    }
    for (int t = tid; t < 64*25; t += 256) {        // w3: (64,32,5,5)
        int oc = t / 25, pos = t % 25;
        unsigned int mk = 0;
        for (int ic = 0; ic < 32; ++ic)
            if (w3[(oc*32 + ic)*25 + pos] > 0.0f) mk |= 1u << ic;
        w3m[t] = mk;
    }
    for (int t = tid; t < 128; t += 256) {          // fw1: (128,64)
        unsigned long long mk = 0;
        for (int i = 0; i < 64; ++i)
            if (fw1[t*64 + i] > 0.0f) mk |= 1ull << i;
        fw1m[t] = mk;
    }
    for (int t = tid; t < 128; t += 256) {          // fw2: (128,128)
        unsigned long long lo = 0, hi = 0;
        for (int i = 0; i < 64; ++i) {
            if (fw2[t*128 + i]      > 0.0f) lo |= 1ull << i;
            if (fw2[t*128 + 64 + i] > 0.0f) hi |= 1ull << i;
        }
        fw2m[2*t] = lo; fw2m[2*t+1] = hi;
    }
    if (tid < 10) {                                  // fw3: (10,128)
        unsigned long long lo = 0, hi = 0;
        for (int i = 0; i < 64; ++i) {
            if (fw3[tid*128 + i]      > 0.0f) lo |= 1ull << i;
            if (fw3[tid*128 + 64 + i] > 0.0f) hi |= 1ull << i;
        }
        fw3m[2*tid] = lo; fw3m[2*tid+1] = hi;
    }
}

// ---------------------------------------------------------------------------
// Kernel A: conv1 (fp32, binarized weights) + pool + sign -> u16 masks.
// One block per image. thread = (oc in 0..15, py in 0..13); computes output
// rows 2py and 2py+1 (28 wide each), pools, sign-tests, ballot-packs 16 ch.
// fp64 recompute for pooled maxima within 1e-3 of threshold (exact signs).
// ---------------------------------------------------------------------------
__global__ __launch_bounds__(256) void convpool1_kernel(
    const float* __restrict__ x, const float* __restrict__ w1,
    const float* __restrict__ t1, unsigned short* __restrict__ a1)
{
    __shared__ float xs[3*32*36];   // rows padded to 36 floats (bank spread)
    __shared__ float ws[16*75];     // binarized w1 as +-1.0f
    __shared__ float t1s[16];

    const int n = blockIdx.x;
    const int tid = threadIdx.x;

    // stage x (3*32*32 floats), padded rows
    const float4* xg = (const float4*)(x + (size_t)n * 3072);
    for (int i = tid; i < 768; i += 256) {
        float4 v = xg[i];
        int c = i >> 8, f4 = i & 255;
        int y = f4 >> 3, xq = f4 & 7;
        *(float4*)(xs + (c*32 + y)*36 + 4*xq) = v;
    }
    for (int i = tid; i < 1200; i += 256)
        ws[i] = (w1[i] > 0.0f) ? 1.0f : -1.0f;
    if (tid < 16) t1s[tid] = t1[tid];
    __syncthreads();

    if (tid < 224) {
        const int oc = tid & 15, py = tid >> 4;
        const float thr = t1s[oc];
        const float* wp = ws + oc*75;

        float hmax[14];
        #pragma unroll
        for (int pass = 0; pass < 2; ++pass) {
            const int oy = 2*py + pass;
            float acc[28];
            #pragma unroll
            for (int i = 0; i < 28; ++i) acc[i] = 0.0f;
            for (int ck = 0; ck < 15; ++ck) {       // c*5 + ky
                const int c = ck / 5, ky = ck % 5;
                const float* xr = xs + (c*32 + oy + ky)*36;
                float xv[32];
                #pragma unroll
                for (int j = 0; j < 8; ++j) {
                    float4 t = *(const float4*)(xr + 4*j);
                    xv[4*j] = t.x; xv[4*j+1] = t.y; xv[4*j+2] = t.z; xv[4*j+3] = t.w;
                }
                #pragma unroll
                for (int kx = 0; kx < 5; ++kx) {
                    float w = wp[c*25 + ky*5 + kx];
                    #pragma unroll
                    for (int ox = 0; ox < 28; ++ox)
                        acc[ox] = fmaf(w, xv[ox + kx], acc[ox]);
                }
            }
            #pragma unroll
            for (int px = 0; px < 14; ++px) {
                float h = fmaxf(acc[2*px], acc[2*px+1]);
                hmax[px] = (pass == 0) ? h : fmaxf(hmax[px], h);
            }
        }

        unsigned int bitsm = 0, flagm = 0;
        #pragma unroll
        for (int px = 0; px < 14; ++px) {
            bitsm |= (unsigned int)(hmax[px] > thr) << px;
            flagm |= (unsigned int)(fabsf(hmax[px] - thr) < 1e-3f) << px;
        }
        // rare exact (fp64) recompute near the sign boundary
        while (flagm) {
            int px = __builtin_ctz(flagm);
            flagm &= flagm - 1;
            double md = -1e300;
            #pragma unroll 1
            for (int d = 0; d < 4; ++d) {
                int oy = 2*py + (d >> 1), ox = 2*px + (d & 1);
                double s = 0.0;
                #pragma unroll 1
                for (int c = 0; c < 3; ++c)
                    #pragma unroll 1
                    for (int ky = 0; ky < 5; ++ky)
                        #pragma unroll 1
                        for (int kx = 0; kx < 5; ++kx)
                            s += (double)wp[c*25 + ky*5 + kx] *
                                 (double)xs[(c*32 + oy + ky)*36 + ox + kx];
                md = fmax(md, s);
            }
            unsigned int b = (md > (double)thr) ? 1u : 0u;
            bitsm = (bitsm & ~(1u << px)) | (b << px);
        }

        // ballot-pack: wave = 4 py-groups x 16 oc
        const int lane = tid & 63;
        #pragma unroll
        for (int px = 0; px < 14; ++px) {
            unsigned long long m = __ballot((bitsm >> px) & 1);
            if ((lane & 15) == 0)
                a1[(size_t)n*196 + py*14 + px] =
                    (unsigned short)(m >> (lane & 48));
        }
    }
}

// ---------------------------------------------------------------------------
// Kernel B: conv2 (xor/popc on 16-bit masks) + pool + sign -> u32 masks.
// Block = 256 threads = 8 images x 32 oc. a1 tiles staged in LDS.
// ---------------------------------------------------------------------------
__global__ __launch_bounds__(256) void convpool2_kernel(
    const unsigned short* __restrict__ a1, const unsigned int* __restrict__ w2m,
    const float* __restrict__ t2, unsigned int* __restrict__ a2)
{
    __shared__ unsigned int tile[8][14][16];
    const int tid = threadIdx.x;
    const int n0 = blockIdx.x * 8;

    for (int i = tid; i < 8*196; i += 256) {
        int img = i / 196, j = i % 196;
        tile[img][j / 14][j % 14] = (unsigned int)a1[(size_t)(n0 + img)*196 + j];
    }
    __syncthreads();

    const int img = tid >> 5, oc = tid & 31;
    unsigned int w[25];
    #pragma unroll
    for (int k = 0; k < 25; ++k) w[k] = w2m[oc*25 + k];
    const float thr = t2[oc];

    unsigned int bits = 0;
    int hmin[5];
    for (int oy = 0; oy < 10; ++oy) {
        unsigned int xr[5][14];
        #pragma unroll
        for (int r = 0; r < 5; ++r)
            #pragma unroll
            for (int j = 0; j < 14; ++j) xr[r][j] = tile[img][oy + r][j];
        int X[10];
        #pragma unroll
        for (int ox = 0; ox < 10; ++ox) {
            int s = 0;
            #pragma unroll
            for (int ky = 0; ky < 5; ++ky)
                #pragma unroll
                for (int kx = 0; kx < 5; ++kx)
                    s += __popc(xr[ky][ox + kx] ^ w[ky*5 + kx]);
            X[ox] = s;
        }
        #pragma unroll
        for (int px = 0; px < 5; ++px) {
            int h = min(X[2*px], X[2*px+1]);
            if ((oy & 1) == 0) hmin[px] = h;
            else {
                int mn = min(hmin[px], h);
                float maxd = (float)(400 - 2*mn);   // max over 2x2 of dot
                if (maxd > thr) bits |= 1u << ((oy >> 1)*5 + px);
            }
        }
    }

    const int lane = tid & 63;
    #pragma unroll
    for (int cell = 0; cell < 25; ++cell) {
        unsigned long long m = __ballot((bits >> cell) & 1);
        if (lane == 0)  a2[(size_t)(n0 + img)*25 + cell] = (unsigned int)m;
        if (lane == 32) a2[(size_t)(n0 + img)*25 + cell] = (unsigned int)(m >> 32);
    }
}

// ---------------------------------------------------------------------------
// Kernel C: conv3 + fc1 + fc2 + fc3 + log_softmax. One wave per image.
// Activations live as ballot masks (a3: 64b, a4/a5: 2x64b) in every lane.
// ---------------------------------------------------------------------------
__global__ __launch_bounds__(256) void tail_kernel(
    const unsigned int* __restrict__ a2,
    const unsigned int* __restrict__ w3m, const float* __restrict__ t3,
    const unsigned long long* __restrict__ fw1m, const float* __restrict__ tc1,
    const unsigned long long* __restrict__ fw2m, const float* __restrict__ tc2,
    const unsigned long long* __restrict__ fw3m,
    const float* __restrict__ cm3, const float* __restrict__ cv3,
    float* __restrict__ out)
{
    const int tid = threadIdx.x;
    const int lane = tid & 63;
    const int n = blockIdx.x*4 + (tid >> 6);

    unsigned int av[25];
    #pragma unroll
    for (int k = 0; k < 25; ++k) av[k] = a2[(size_t)n*25 + k];

    // conv3: lane = output channel
    int X = 0;
    #pragma unroll
    for (int k = 0; k < 25; ++k) X += __popc(av[k] ^ w3m[lane*25 + k]);
    float d3 = (float)(800 - 2*X);
    unsigned long long a3 = __ballot(d3 > t3[lane]);

    // fc1: lane handles outputs lane and lane+64
    int o1 = lane + 64;
    int d0 = 64 - 2*__popcll(a3 ^ fw1m[lane]);
    int d1 = 64 - 2*__popcll(a3 ^ fw1m[o1]);
    unsigned long long a4lo = __ballot((float)d0 > tc1[lane]);
    unsigned long long a4hi = __ballot((float)d1 > tc1[o1]);

    // fc2
    int e0 = 128 - 2*(__popcll(a4lo ^ fw2m[2*lane])   + __popcll(a4hi ^ fw2m[2*lane+1]));
    int e1 = 128 - 2*(__popcll(a4lo ^ fw2m[2*o1])     + __popcll(a4hi ^ fw2m[2*o1+1]));
    unsigned long long a5lo = __ballot((float)e0 > tc2[lane]);
    unsigned long long a5hi = __ballot((float)e1 > tc2[o1]);

    // fc3 + bn1d on lanes 0..9
    float y = -1e30f;
    if (lane < 10) {
        int f = 128 - 2*(__popcll(a5lo ^ fw3m[2*lane]) + __popcll(a5hi ^ fw3m[2*lane+1]));
        y = ((float)f - cm3[lane]) / sqrtf(cv3[lane] + EPS);
    }
    // log_softmax across lanes 0..9 (reduce over 16-lane group)
    float m = y;
    #pragma unroll
    for (int off = 8; off > 0; off >>= 1) m = fmaxf(m, __shfl_xor(m, off, 16));
    float s = (lane < 10) ? expf(y - m) : 0.0f;
    #pragma unroll
    for (int off = 8; off > 0; off >>= 1) s += __shfl_xor(s, off, 16);
    if (lane < 10) out[(size_t)n*10 + lane] = y - m - logf(s);
}

// ---------------------------------------------------------------------------
extern "C" void kernel_launch(void* const* d_in, const int* in_sizes, int n_in,
                              void* d_out, int out_size, void* d_ws, size_t ws_size,
                              hipStream_t stream)
{
    const float* x   = (const float*)d_in[0];
    const float* w1  = (const float*)d_in[1];
    const float* b1  = (const float*)d_in[2];
    const float* g1  = (const float*)d_in[3];
    const float* be1 = (const float*)d_in[4];
    const float* m1  = (const float*)d_in[5];
    const float* v1  = (const float*)d_in[6];
    const float* w2  = (const float*)d_in[7];
    const float* b2  = (const float*)d_in[8];
    const float* g2  = (const float*)d_in[9];
    const float* be2 = (const float*)d_in[10];
    const float* m2  = (const float*)d_in[11];
    const float* v2  = (const float*)d_in[12];
    const float* w3  = (const float*)d_in[13];
    const float* b3  = (const float*)d_in[14];
    const float* g3  = (const float*)d_in[15];
    const float* be3 = (const float*)d_in[16];
    const float* m3  = (const float*)d_in[17];
    const float* v3  = (const float*)d_in[18];
    const float* fw1 = (const float*)d_in[19];
    const float* fb1 = (const float*)d_in[20];
    const float* cm1 = (const float*)d_in[21];
    const float* fw2 = (const float*)d_in[23];
    const float* fb2 = (const float*)d_in[24];
    const float* cm2 = (const float*)d_in[25];
    const float* fw3 = (const float*)d_in[27];
    const float* cm3 = (const float*)d_in[28];
    const float* cv3 = (const float*)d_in[29];

    char* ws = (char*)d_ws;
    unsigned short*     a1   = (unsigned short*)(ws + A1_OFF);
    unsigned int*       a2   = (unsigned int*)(ws + A2_OFF);
    unsigned int*       w2m  = (unsigned int*)(ws + W2M_OFF);
    unsigned int*       w3m  = (unsigned int*)(ws + W3M_OFF);
    unsigned long long* fw1m = (unsigned long long*)(ws + FW1M_OFF);
    unsigned long long* fw2m = (unsigned long long*)(ws + FW2M_OFF);
    unsigned long long* fw3m = (unsigned long long*)(ws + FW3M_OFF);
    float* t1  = (float*)(ws + T1_OFF);
    float* t2  = (float*)(ws + T2_OFF);
    float* t3  = (float*)(ws + T3_OFF);
    float* tc1 = (float*)(ws + TC1_OFF);
    float* tc2 = (float*)(ws + TC2_OFF);

    setup_kernel<<<1, 256, 0, stream>>>(
        w2, w3, fw1, fw2, fw3,
        b1, g1, be1, m1, v1,
        b2, g2, be2, m2, v2,
        b3, g3, be3, m3, v3,
        fb1, cm1, fb2, cm2,
        w2m, w3m, fw1m, fw2m, fw3m, t1, t2, t3, tc1, tc2);

    convpool1_kernel<<<8192, 256, 0, stream>>>(x, w1, t1, a1);
    convpool2_kernel<<<1024, 256, 0, stream>>>(a1, w2m, t2, a2);
    tail_kernel<<<2048, 256, 0, stream>>>(a2, w3m, t3, fw1m, tc1, fw2m, tc2,
                                          fw3m, cm3, cv3, (float*)d_out);
}

// Round 2
// 437.184 us; speedup vs baseline: 1.0453x; 1.0453x over previous
//
#include <hip/hip_runtime.h>
#include <cstdint>

#define EPS 1e-5f

// ---- workspace layout (bytes) ----
#define A1_OFF   0ull                 // 8192*196 u16 = 8192*98 u32 (a1 bitmasks)
#define A2_OFF   3211264ull           // 8192*25  u32  (a2 bitmasks, 32 ch)
#define W2M_OFF  4030464ull           // 32*25 u32
#define W3M_OFF  4033664ull           // 64*25 u32
#define FW1M_OFF 4040064ull           // 128 u64
#define FW2M_OFF 4041088ull           // 128*2 u64
#define FW3M_OFF 4043136ull           // 10*2 u64
#define T1_OFF   4043296ull           // 16 f32
#define T2_OFF   4043360ull           // 32 f32
#define T3_OFF   4043488ull           // 64 f32
#define TC1_OFF  4043744ull           // 128 f32
#define TC2_OFF  4044256ull           // 128 f32

// ---------------------------------------------------------------------------
// Setup (grid=4, work split by blockIdx): pack binarized weights to bitmasks,
// fold bn+bias into thresholds.  value > thr  <=>  bn(value+bias) > 0 (g>0)
// ---------------------------------------------------------------------------
__global__ void setup_kernel(
    const float* __restrict__ w2, const float* __restrict__ w3,
    const float* __restrict__ fw1, const float* __restrict__ fw2,
    const float* __restrict__ fw3,
    const float* __restrict__ b1, const float* __restrict__ g1,
    const float* __restrict__ be1, const float* __restrict__ m1,
    const float* __restrict__ v1,
    const float* __restrict__ b2, const float* __restrict__ g2,
    const float* __restrict__ be2, const float* __restrict__ m2,
    const float* __restrict__ v2,
    const float* __restrict__ b3, const float* __restrict__ g3,
    const float* __restrict__ be3, const float* __restrict__ m3,
    const float* __restrict__ v3,
    const float* __restrict__ fb1, const float* __restrict__ cm1,
    const float* __restrict__ fb2, const float* __restrict__ cm2,
    unsigned int* __restrict__ w2m, unsigned int* __restrict__ w3m,
    unsigned long long* __restrict__ fw1m, unsigned long long* __restrict__ fw2m,
    unsigned long long* __restrict__ fw3m,
    float* __restrict__ t1, float* __restrict__ t2, float* __restrict__ t3,
    float* __restrict__ tc1, float* __restrict__ tc2)
{
    const int tid = threadIdx.x;
    const int blk = blockIdx.x;

    if (blk == 0) {
        if (tid < 16) t1[tid] = m1[tid] - be1[tid]*sqrtf(v1[tid]+EPS)/g1[tid] - b1[tid];
        if (tid < 32) t2[tid] = m2[tid] - be2[tid]*sqrtf(v2[tid]+EPS)/g2[tid] - b2[tid];
        if (tid < 64) t3[tid] = m3[tid] - be3[tid]*sqrtf(v3[tid]+EPS)/g3[tid] - b3[tid];
        if (tid < 128) { tc1[tid] = cm1[tid] - fb1[tid]; tc2[tid] = cm2[tid] - fb2[tid]; }
        for (int t = tid; t < 32*25; t += 256) {        // w2: (32,16,5,5)
            int oc = t / 25, pos = t % 25;
            unsigned int mk = 0;
            for (int ic = 0; ic < 16; ++ic)
                if (w2[(oc*16 + ic)*25 + pos] > 0.0f) mk |= 1u << ic;
            w2m[t] = mk;
        }
    } else if (blk == 1) {
        for (int t = tid; t < 64*25; t += 256) {        // w3: (64,32,5,5)
            int oc = t / 25, pos = t % 25;
            unsigned int mk = 0;
            for (int ic = 0; ic < 32; ++ic)
                if (w3[(oc*32 + ic)*25 + pos] > 0.0f) mk |= 1u << ic;
            w3m[t] = mk;
        }
    } else if (blk == 2) {
        for (int t = tid; t < 128; t += 256) {          // fw1: (128,64)
            unsigned long long mk = 0;
            for (int i = 0; i < 64; ++i)
                if (fw1[t*64 + i] > 0.0f) mk |= 1ull << i;
            fw1m[t] = mk;
        }
    } else {
        for (int t = tid; t < 128; t += 256) {          // fw2: (128,128)
            unsigned long long lo = 0, hi = 0;
            for (int i = 0; i < 64; ++i) {
                if (fw2[t*128 + i]      > 0.0f) lo |= 1ull << i;
                if (fw2[t*128 + 64 + i] > 0.0f) hi |= 1ull << i;
            }
            fw2m[2*t] = lo; fw2m[2*t+1] = hi;
        }
        if (tid < 10) {                                  // fw3: (10,128)
            unsigned long long lo = 0, hi = 0;
            for (int i = 0; i < 64; ++i) {
                if (fw3[tid*128 + i]      > 0.0f) lo |= 1ull << i;
                if (fw3[tid*128 + 64 + i] > 0.0f) hi |= 1ull << i;
            }
            fw3m[2*tid] = lo; fw3m[2*tid+1] = hi;
        }
    }
}

// ---------------------------------------------------------------------------
// Kernel A: conv1 (fp32, binarized weights) + pool + sign -> packed u32 masks.
// Block = 128 threads, 1 image. Active thread = (py 0..13, ocg 0..7); handles
// oc = ocg and ocg+8 (2 oc share every x load and all addressing).
// fp64 recompute for pooled maxima within 1e-3 of threshold (exact signs).
// ---------------------------------------------------------------------------
__global__ __launch_bounds__(128) void convpool1_kernel(
    const float* __restrict__ x, const float* __restrict__ w1,
    const float* __restrict__ t1, unsigned int* __restrict__ a1u)
{
    __shared__ float xs[3*32*36];        // rows padded to 36 floats
    __shared__ float ws[16*75];          // binarized w1 as +-1.0f
    __shared__ unsigned int pk[196];     // per-(py,px) 16-oc bit accumulators
    __shared__ float t1s[16];

    const int n = blockIdx.x;
    const int tid = threadIdx.x;

    const float4* xg = (const float4*)(x + (size_t)n * 3072);
    for (int i = tid; i < 768; i += 128) {
        float4 v = xg[i];
        int c = i >> 8, f4 = i & 255, y = f4 >> 3, xq = f4 & 7;
        *(float4*)(xs + (c*32 + y)*36 + 4*xq) = v;
    }
    for (int i = tid; i < 1200; i += 128)
        ws[i] = (w1[i] > 0.0f) ? 1.0f : -1.0f;
    for (int i = tid; i < 196; i += 128) pk[i] = 0;
    if (tid < 16) t1s[tid] = t1[tid];
    __syncthreads();

    if (tid < 112) {
        const int py = tid >> 3, ocg = tid & 7;
        const int oc0 = ocg, oc1 = ocg + 8;
        const float* wp0 = ws + oc0*75;
        const float* wp1 = ws + oc1*75;
        const float thr0 = t1s[oc0], thr1 = t1s[oc1];

        float hmax0[14], hmax1[14];
        #pragma unroll
        for (int pass = 0; pass < 2; ++pass) {
            const int oy = 2*py + pass;
            float acc0[28], acc1[28];
            #pragma unroll
            for (int i = 0; i < 28; ++i) { acc0[i] = 0.0f; acc1[i] = 0.0f; }
            #pragma unroll 3
            for (int ck = 0; ck < 15; ++ck) {           // ck = c*5 + ky
                const int c = ck / 5, ky = ck % 5;
                const float* xr = xs + (c*32 + oy + ky)*36;
                float xv[32];
                #pragma unroll
                for (int j = 0; j < 8; ++j) {
                    float4 t = *(const float4*)(xr + 4*j);
                    xv[4*j] = t.x; xv[4*j+1] = t.y; xv[4*j+2] = t.z; xv[4*j+3] = t.w;
                }
                #pragma unroll
                for (int kx = 0; kx < 5; ++kx) {
                    const float w0 = wp0[ck*5 + kx];
                    const float w1v = wp1[ck*5 + kx];
                    #pragma unroll
                    for (int ox = 0; ox < 28; ++ox) {
                        acc0[ox] = fmaf(w0,  xv[ox + kx], acc0[ox]);
                        acc1[ox] = fmaf(w1v, xv[ox + kx], acc1[ox]);
                    }
                }
            }
            #pragma unroll
            for (int px = 0; px < 14; ++px) {
                float h0 = fmaxf(acc0[2*px], acc0[2*px+1]);
                float h1 = fmaxf(acc1[2*px], acc1[2*px+1]);
                if (pass == 0) { hmax0[px] = h0; hmax1[px] = h1; }
                else { hmax0[px] = fmaxf(hmax0[px], h0); hmax1[px] = fmaxf(hmax1[px], h1); }
            }
        }

        unsigned int bits0 = 0, bits1 = 0, flag0 = 0, flag1 = 0;
        #pragma unroll
        for (int px = 0; px < 14; ++px) {
            bits0 |= (unsigned int)(hmax0[px] > thr0) << px;
            bits1 |= (unsigned int)(hmax1[px] > thr1) << px;
            flag0 |= (unsigned int)(fabsf(hmax0[px] - thr0) < 1e-3f) << px;
            flag1 |= (unsigned int)(fabsf(hmax1[px] - thr1) < 1e-3f) << px;
        }
        // rare exact (fp64) recompute near the sign boundary
        #pragma unroll 1
        for (int which = 0; which < 2; ++which) {
            unsigned int flagm = which ? flag1 : flag0;
            const float* wp = which ? wp1 : wp0;
            const float thr = which ? thr1 : thr0;
            while (flagm) {
                int px = __builtin_ctz(flagm);
                flagm &= flagm - 1;
                double md = -1e300;
                #pragma unroll 1
                for (int d = 0; d < 4; ++d) {
                    int oy = 2*py + (d >> 1), ox = 2*px + (d & 1);
                    double s = 0.0;
                    #pragma unroll 1
                    for (int c = 0; c < 3; ++c)
                        #pragma unroll 1
                        for (int ky = 0; ky < 5; ++ky)
                            #pragma unroll 1
                            for (int kx = 0; kx < 5; ++kx)
                                s += (double)wp[c*25 + ky*5 + kx] *
                                     (double)xs[(c*32 + oy + ky)*36 + ox + kx];
                    md = fmax(md, s);
                }
                unsigned int b = (md > (double)thr) ? 1u : 0u;
                if (which) bits1 = (bits1 & ~(1u << px)) | (b << px);
                else       bits0 = (bits0 & ~(1u << px)) | (b << px);
            }
        }

        #pragma unroll
        for (int px = 0; px < 14; ++px) {
            unsigned int v = (((bits0 >> px) & 1u) << oc0) | (((bits1 >> px) & 1u) << oc1);
            if (v) atomicOr(&pk[py*14 + px], v);
        }
    }
    __syncthreads();
    for (int i = tid; i < 98; i += 128)
        a1u[(size_t)n*98 + i] = pk[2*i] | (pk[2*i+1] << 16);
}

// ---------------------------------------------------------------------------
// Kernel B: conv2 via xor/popc with PAIR-PACKED taps (two 16-bit masks per
// u32 popc) + pool + sign -> u32 masks. Block = 8 images x 32 oc.
// ---------------------------------------------------------------------------
__global__ __launch_bounds__(256) void convpool2_kernel(
    const unsigned int* __restrict__ a1u, const unsigned int* __restrict__ w2m,
    const float* __restrict__ t2, unsigned int* __restrict__ a2)
{
    __shared__ unsigned int M[8][14][16];   // raw 16-bit masks (zero-extended)
    __shared__ unsigned int P[8][14][16];   // P[y][j] = M[y][j] | M[y][j+1]<<16
    __shared__ unsigned int Q[8][13][16];   // Q[y][j] = M[y][j] | M[y+1][j]<<16
    const int tid = threadIdx.x;
    const int n0 = blockIdx.x * 8;

    for (int i = tid; i < 8*98; i += 256) {
        unsigned int v = a1u[(size_t)n0*98 + i];
        int e = 2*i;
        int img = e / 196, r = e - img*196;
        int y0 = r / 14, c0 = r - y0*14;
        int r1 = r + 1, y1 = r1 / 14, c1 = r1 - y1*14;
        M[img][y0][c0] = v & 0xffffu;
        M[img][y1][c1] = v >> 16;
    }
    __syncthreads();
    for (int i = tid; i < 8*14*13; i += 256) {
        int img = i / 182, r = i - img*182, y = r / 13, j = r - y*13;
        P[img][y][j] = M[img][y][j] | (M[img][y][j+1] << 16);
    }
    for (int i = tid; i < 8*13*14; i += 256) {
        int img = i / 182, r = i - img*182, y = r / 14, j = r - y*14;
        Q[img][y][j] = M[img][y][j] | (M[img][y+1][j] << 16);
    }
    __syncthreads();

    const int img = tid >> 5, oc = tid & 31;
    unsigned int w[25];
    #pragma unroll
    for (int k = 0; k < 25; ++k) w[k] = w2m[oc*25 + k];
    unsigned int wp[5][2], wc0, wc1, wcs;
    #pragma unroll
    for (int ky = 0; ky < 5; ++ky) {
        wp[ky][0] = w[ky*5]     | (w[ky*5+1] << 16);
        wp[ky][1] = w[ky*5 + 2] | (w[ky*5+3] << 16);
    }
    wc0 = w[4]  | (w[9]  << 16);
    wc1 = w[14] | (w[19] << 16);
    wcs = w[24];
    const float thr = t2[oc];

    unsigned int bits = 0;
    int hprev[5];
    #pragma unroll 2
    for (int oy = 0; oy < 10; ++oy) {
        unsigned int Pr[5][12];
        #pragma unroll
        for (int ky = 0; ky < 5; ++ky) {
            const uint4* pr = (const uint4*)&P[img][oy + ky][0];
            uint4 a = pr[0], b = pr[1], c = pr[2];
            Pr[ky][0]=a.x; Pr[ky][1]=a.y; Pr[ky][2]=a.z; Pr[ky][3]=a.w;
            Pr[ky][4]=b.x; Pr[ky][5]=b.y; Pr[ky][6]=b.z; Pr[ky][7]=b.w;
            Pr[ky][8]=c.x; Pr[ky][9]=c.y; Pr[ky][10]=c.z; Pr[ky][11]=c.w;
        }
        unsigned int Qa[10], Qb[10], Ms[10];
        {
            const uint4* qa = (const uint4*)&Q[img][oy][4];
            const uint2* qa2 = (const uint2*)&Q[img][oy][12];
            uint4 a = qa[0], b = qa[1]; uint2 c = qa2[0];
            Qa[0]=a.x; Qa[1]=a.y; Qa[2]=a.z; Qa[3]=a.w;
            Qa[4]=b.x; Qa[5]=b.y; Qa[6]=b.z; Qa[7]=b.w; Qa[8]=c.x; Qa[9]=c.y;
            const uint4* qb = (const uint4*)&Q[img][oy+2][4];
            const uint2* qb2 = (const uint2*)&Q[img][oy+2][12];
            uint4 d = qb[0], e = qb[1]; uint2 f = qb2[0];
            Qb[0]=d.x; Qb[1]=d.y; Qb[2]=d.z; Qb[3]=d.w;
            Qb[4]=e.x; Qb[5]=e.y; Qb[6]=e.z; Qb[7]=e.w; Qb[8]=f.x; Qb[9]=f.y;
            const uint4* ms = (const uint4*)&M[img][oy+4][4];
            const uint2* ms2 = (const uint2*)&M[img][oy+4][12];
            uint4 g = ms[0], h = ms[1]; uint2 k2 = ms2[0];
            Ms[0]=g.x; Ms[1]=g.y; Ms[2]=g.z; Ms[3]=g.w;
            Ms[4]=h.x; Ms[5]=h.y; Ms[6]=h.z; Ms[7]=h.w; Ms[8]=k2.x; Ms[9]=k2.y;
        }
        int X[10];
        #pragma unroll
        for (int ox = 0; ox < 10; ++ox) {
            int s = 0;
            #pragma unroll
            for (int ky = 0; ky < 5; ++ky)
                s += __popc(Pr[ky][ox] ^ wp[ky][0]) + __popc(Pr[ky][ox+2] ^ wp[ky][1]);
            s += __popc(Qa[ox] ^ wc0) + __popc(Qb[ox] ^ wc1) + __popc(Ms[ox] ^ wcs);
            X[ox] = s;
        }
        #pragma unroll
        for (int px = 0; px < 5; ++px) {
            int h = min(X[2*px], X[2*px+1]);
            if ((oy & 1) == 0) hprev[px] = h;
            else {
                int mn = min(hprev[px], h);
                if ((float)(400 - 2*mn) > thr) bits |= 1u << ((oy >> 1)*5 + px);
            }
        }
    }

    const int lane = tid & 63;
    #pragma unroll
    for (int cell = 0; cell < 25; ++cell) {
        unsigned long long m = __ballot((bits >> cell) & 1);
        if (lane == 0)  a2[(size_t)(n0 + img)*25 + cell] = (unsigned int)m;
        if (lane == 32) a2[(size_t)(n0 + img)*25 + cell] = (unsigned int)(m >> 32);
    }
}

// ---------------------------------------------------------------------------
// Kernel C: conv3 + fc1 + fc2 + fc3 + log_softmax. One wave per image.
// ---------------------------------------------------------------------------
__global__ __launch_bounds__(256) void tail_kernel(
    const unsigned int* __restrict__ a2,
    const unsigned int* __restrict__ w3m, const float* __restrict__ t3,
    const unsigned long long* __restrict__ fw1m, const float* __restrict__ tc1,
    const unsigned long long* __restrict__ fw2m, const float* __restrict__ tc2,
    const unsigned long long* __restrict__ fw3m,
    const float* __restrict__ cm3, const float* __restrict__ cv3,
    float* __restrict__ out)
{
    __shared__ unsigned int w3s[64*25];
    const int tid = threadIdx.x;
    for (int i = tid; i < 1600; i += 256) w3s[i] = w3m[i];
    __syncthreads();

    const int lane = tid & 63;
    const int n = blockIdx.x*4 + (tid >> 6);

    unsigned int av[25];
    #pragma unroll
    for (int k = 0; k < 25; ++k) av[k] = a2[(size_t)n*25 + k];

    // conv3: lane = output channel (w3s stride 25 mod 32: conflict-free perm)
    int X = 0;
    #pragma unroll
    for (int k = 0; k < 25; ++k) X += __popc(av[k] ^ w3s[lane*25 + k]);
    float d3 = (float)(800 - 2*X);
    unsigned long long a3 = __ballot(d3 > t3[lane]);

    // fc1: lane handles outputs lane and lane+64
    int o1 = lane + 64;
    int d0 = 64 - 2*(int)__popcll(a3 ^ fw1m[lane]);
    int d1 = 64 - 2*(int)__popcll(a3 ^ fw1m[o1]);
    unsigned long long a4lo = __ballot((float)d0 > tc1[lane]);
    unsigned long long a4hi = __ballot((float)d1 > tc1[o1]);

    // fc2
    int e0 = 128 - 2*(int)(__popcll(a4lo ^ fw2m[2*lane]) + __popcll(a4hi ^ fw2m[2*lane+1]));
    int e1 = 128 - 2*(int)(__popcll(a4lo ^ fw2m[2*o1])   + __popcll(a4hi ^ fw2m[2*o1+1]));
    unsigned long long a5lo = __ballot((float)e0 > tc2[lane]);
    unsigned long long a5hi = __ballot((float)e1 > tc2[o1]);

    // fc3 + bn1d on lanes 0..9
    float y = -1e30f;
    if (lane < 10) {
        int f = 128 - 2*(int)(__popcll(a5lo ^ fw3m[2*lane]) + __popcll(a5hi ^ fw3m[2*lane+1]));
        y = ((float)f - cm3[lane]) / sqrtf(cv3[lane] + EPS);
    }
    float m = y;
    #pragma unroll
    for (int off = 8; off > 0; off >>= 1) m = fmaxf(m, __shfl_xor(m, off, 16));
    float s = (lane < 10) ? expf(y - m) : 0.0f;
    #pragma unroll
    for (int off = 8; off > 0; off >>= 1) s += __shfl_xor(s, off, 16);
    if (lane < 10) out[(size_t)n*10 + lane] = y - m - logf(s);
}

// ---------------------------------------------------------------------------
extern "C" void kernel_launch(void* const* d_in, const int* in_sizes, int n_in,
                              void* d_out, int out_size, void* d_ws, size_t ws_size,
                              hipStream_t stream)
{
    const float* x   = (const float*)d_in[0];
    const float* w1  = (const float*)d_in[1];
    const float* b1  = (const float*)d_in[2];
    const float* g1  = (const float*)d_in[3];
    const float* be1 = (const float*)d_in[4];
    const float* m1  = (const float*)d_in[5];
    const float* v1  = (const float*)d_in[6];
    const float* w2  = (const float*)d_in[7];
    const float* b2  = (const float*)d_in[8];
    const float* g2  = (const float*)d_in[9];
    const float* be2 = (const float*)d_in[10];
    const float* m2  = (const float*)d_in[11];
    const float* v2  = (const float*)d_in[12];
    const float* w3  = (const float*)d_in[13];
    const float* b3  = (const float*)d_in[14];
    const float* g3  = (const float*)d_in[15];
    const float* be3 = (const float*)d_in[16];
    const float* m3  = (const float*)d_in[17];
    const float* v3  = (const float*)d_in[18];
    const float* fw1 = (const float*)d_in[19];
    const float* fb1 = (const float*)d_in[20];
    const float* cm1 = (const float*)d_in[21];
    const float* fw2 = (const float*)d_in[23];
    const float* fb2 = (const float*)d_in[24];
    const float* cm2 = (const float*)d_in[25];
    const float* fw3 = (const float*)d_in[27];
    const float* cm3 = (const float*)d_in[28];
    const float* cv3 = (const float*)d_in[29];

    char* ws = (char*)d_ws;
    unsigned int*       a1u  = (unsigned int*)(ws + A1_OFF);
    unsigned int*       a2   = (unsigned int*)(ws + A2_OFF);
    unsigned int*       w2m  = (unsigned int*)(ws + W2M_OFF);
    unsigned int*       w3m  = (unsigned int*)(ws + W3M_OFF);
    unsigned long long* fw1m = (unsigned long long*)(ws + FW1M_OFF);
    unsigned long long* fw2m = (unsigned long long*)(ws + FW2M_OFF);
    unsigned long long* fw3m = (unsigned long long*)(ws + FW3M_OFF);
    float* t1  = (float*)(ws + T1_OFF);
    float* t2  = (float*)(ws + T2_OFF);
    float* t3  = (float*)(ws + T3_OFF);
    float* tc1 = (float*)(ws + TC1_OFF);
    float* tc2 = (float*)(ws + TC2_OFF);

    setup_kernel<<<4, 256, 0, stream>>>(
        w2, w3, fw1, fw2, fw3,
        b1, g1, be1, m1, v1,
        b2, g2, be2, m2, v2,
        b3, g3, be3, m3, v3,
        fb1, cm1, fb2, cm2,
        w2m, w3m, fw1m, fw2m, fw3m, t1, t2, t3, tc1, tc2);

    convpool1_kernel<<<8192, 128, 0, stream>>>(x, w1, t1, a1u);
    convpool2_kernel<<<1024, 256, 0, stream>>>(a1u, w2m, t2, a2);
    tail_kernel<<<2048, 256, 0, stream>>>(a2, w3m, t3, fw1m, tc1, fw2m, tc2,
                                          fw3m, cm3, cv3, (float*)d_out);
}